// Round 1
// baseline (442.280 us; speedup 1.0000x reference)
//
#include <hip/hip_runtime.h>
#include <math.h>

#define NS 4
#define NC 128
#define HH 64
#define WW 64
#define LL 1024   // 32*32

// ---------------- prep: f_s [s][c][q], b_s [s][c][p]  (stride-2 subsample, c-major)
__global__ __launch_bounds__(256) void prep_fs_bs(const float* __restrict__ f,
                                                  const float* __restrict__ b,
                                                  float* __restrict__ fs,
                                                  float* __restrict__ bs) {
  int idx = blockIdx.x * 256 + threadIdx.x;      // NS*NC*LL = 524288
  if (idx >= NS * NC * LL) return;
  int q  = idx & (LL - 1);
  int c  = (idx >> 10) & (NC - 1);
  int s  = idx >> 17;
  int qh = q >> 5, qw = q & 31;
  int g  = ((s * NC + c) * HH + 2 * qh) * WW + 2 * qw;
  fs[idx] = f[g];
  bs[idx] = b[g];
}

// ---------------- prep: bpT[((s*4+cls)*LL + k)*NC + c] = b[s][c][2kh+py][2kw+px]
// (k-major -> c-contiguous, via LDS transpose)
__global__ __launch_bounds__(256) void prep_bparT(const float* __restrict__ b,
                                                  float* __restrict__ bpT) {
  int z   = blockIdx.x;           // s*128 + cls*32 + kh  (512 blocks)
  int kh  = z & 31;
  int cls = (z >> 5) & 3;
  int s   = z >> 7;
  int py  = cls >> 1, px = cls & 1;
  __shared__ float T[32][NC + 1];
  int t  = threadIdx.x;
  int kw = t & 31, cb = t >> 5;   // cb in [0,8)
  for (int r = 0; r < 16; ++r) {
    int c = cb * 16 + r;
    T[kw][c] = b[((s * NC + c) * HH + 2 * kh + py) * WW + 2 * kw + px];
  }
  __syncthreads();
  int c2 = t & 127, kg = t >> 7;  // kg in [0,2)
  for (int r = 0; r < 16; ++r) {
    int kw2 = kg * 16 + r;
    bpT[((size_t)(s * 4 + cls) * LL + kh * 32 + kw2) * NC + c2] = T[kw2][c2];
  }
}

// ---------------- Gram: G[s][p][q] = sum_c bs[s][c][p] * fs[s][c][q]   (M=N=1024, K=128)
__global__ __launch_bounds__(256) void gram(const float* __restrict__ bs,
                                            const float* __restrict__ fs,
                                            float* __restrict__ G) {
  int s  = blockIdx.z;
  int m0 = blockIdx.y * 64;
  int n0 = blockIdx.x * 64;
  const float* A  = bs + (size_t)s * NC * LL;
  const float* Bm = fs + (size_t)s * NC * LL;
  __shared__ float As[16][64];
  __shared__ float Bs2[16][64];
  int t = threadIdx.x;
  int tx = t & 15, ty = t >> 4;
  float acc[4][4] = {};
  for (int k0 = 0; k0 < NC; k0 += 16) {
#pragma unroll
    for (int r = 0; r < 4; ++r) {
      int e = t + r * 256;
      int kk = e >> 6, mm = e & 63;
      As[kk][mm]  = A[(k0 + kk) * LL + m0 + mm];
      Bs2[kk][mm] = Bm[(k0 + kk) * LL + n0 + mm];
    }
    __syncthreads();
#pragma unroll
    for (int kk = 0; kk < 16; ++kk) {
      float4 av = *(const float4*)&As[kk][ty * 4];
      float4 bv = *(const float4*)&Bs2[kk][tx * 4];
      float a[4] = {av.x, av.y, av.z, av.w};
      float bb[4] = {bv.x, bv.y, bv.z, bv.w};
#pragma unroll
      for (int i = 0; i < 4; ++i)
#pragma unroll
        for (int j = 0; j < 4; ++j) acc[i][j] += a[i] * bb[j];
    }
    __syncthreads();
  }
  float* Gs = G + (size_t)s * LL * LL;
#pragma unroll
  for (int i = 0; i < 4; ++i) {
    float4 o = make_float4(acc[i][0], acc[i][1], acc[i][2], acc[i][3]);
    *(float4*)&Gs[(size_t)(m0 + ty * 4 + i) * LL + n0 + tx * 4] = o;
  }
}

// ---------------- norms (patch L2 incl. +1e-4 per element) and mask means
__global__ __launch_bounds__(1024) void norm_mm(const float* __restrict__ bs,
                                                const float* __restrict__ mask,
                                                float* __restrict__ nrm,
                                                float* __restrict__ mmv) {
  int s = blockIdx.x;
  int p = threadIdx.x;             // 1024
  __shared__ float Q[LL];
  __shared__ float M[LL];
  const float* bsp = bs + (size_t)s * NC * LL;
  float q = 0.f;
  for (int c = 0; c < NC; ++c) { float v = bsp[c * LL + p]; q += v * v; }
  Q[p] = q;
  int ph = p >> 5, pw = p & 31;
  M[p] = mask[s * HH * WW + (2 * ph) * WW + 2 * pw];
  __syncthreads();
  float sum2 = 1152 * 1e-4f;       // sum of the +0.0001 terms (128*3*3)
  float msum = 0.f;
#pragma unroll
  for (int dh = -1; dh <= 1; ++dh)
#pragma unroll
    for (int dw = -1; dw <= 1; ++dw) {
      int h = ph + dh, w = pw + dw;
      if (h >= 0 && h < 32 && w >= 0 && w < 32) {
        sum2 += Q[h * 32 + w];
        msum += M[h * 32 + w];
      }
    }
  nrm[s * LL + p] = sqrtf(sum2);
  mmv[s * LL + p] = msum * (1.f / 9.f);
}

// ---------------- S[p][q] = (sum of 9 diagonal 2D taps of G) / norm[p]
__global__ __launch_bounds__(256) void sbuild(const float* __restrict__ G,
                                              const float* __restrict__ nrm,
                                              float* __restrict__ S) {
  int s = blockIdx.z;
  int p = blockIdx.y;
  int q = blockIdx.x * 256 + threadIdx.x;
  int ph = p >> 5, pw = p & 31, qh = q >> 5, qw = q & 31;
  const float* Gs = G + (size_t)s * LL * LL;
  float acc = 0.f;
#pragma unroll
  for (int dh = -1; dh <= 1; ++dh)
#pragma unroll
    for (int dw = -1; dw <= 1; ++dw) {
      int ph2 = ph + dh, pw2 = pw + dw, qh2 = qh + dh, qw2 = qw + dw;
      if (ph2 >= 0 && ph2 < 32 && pw2 >= 0 && pw2 < 32 &&
          qh2 >= 0 && qh2 < 32 && qw2 >= 0 && qw2 < 32)
        acc += Gs[(size_t)(ph2 * 32 + pw2) * LL + qh2 * 32 + qw2];
    }
  S[(size_t)s * LL * LL + (size_t)p * LL + q] = acc / nrm[s * LL + p];
}

// ---------------- fuse pass 1: flat diagonal 3-tap in (I,J)
__global__ __launch_bounds__(256) void fuse1(const float* __restrict__ S,
                                             float* __restrict__ F1) {
  int s = blockIdx.z;
  int I = blockIdx.y;
  int J = blockIdx.x * 256 + threadIdx.x;
  const float* Ss = S + (size_t)s * LL * LL;
  float v = Ss[(size_t)I * LL + J];
  if (I > 0 && J > 0)           v += Ss[(size_t)(I - 1) * LL + J - 1];
  if (I < LL - 1 && J < LL - 1) v += Ss[(size_t)(I + 1) * LL + J + 1];
  F1[(size_t)s * LL * LL + (size_t)I * LL + J] = v;
}

// ---------------- fuse pass 2: diagonal 3-tap in transposed flattening
__global__ __launch_bounds__(256) void fuse2(const float* __restrict__ F1,
                                             float* __restrict__ F2) {
  int s = blockIdx.z;
  int I = blockIdx.y;                        // ibh*32+ibw
  int J = blockIdx.x * 256 + threadIdx.x;    // fhi*32+fwi
  int ibh = I >> 5, ibw = I & 31, fhi = J >> 5, fwi = J & 31;
  int Ip = ibw * 32 + ibh, Jp = fwi * 32 + fhi;
  const float* F = F1 + (size_t)s * LL * LL;
  float v = 0.f;
#pragma unroll
  for (int d = -1; d <= 1; ++d) {
    int a = Ip + d, bb = Jp + d;
    if (a >= 0 && a < LL && bb >= 0 && bb < LL) {
      int I2 = (a & 31) * 32 + (a >> 5);
      int J2 = (bb & 31) * 32 + (bb >> 5);
      v += F[(size_t)I2 * LL + J2];
    }
  }
  F2[(size_t)s * LL * LL + (size_t)I * LL + J] = v;
}

// ---------------- column softmax over p (with mm applied pre/post), write transposed yiT[q][p]
__global__ __launch_bounds__(256) void softmax_k(const float* __restrict__ F2,
                                                 const float* __restrict__ mmv,
                                                 float* __restrict__ yiT) {
  int s  = blockIdx.y;
  int q0 = blockIdx.x * 16;
  int t  = threadIdx.x;
  int qx = t & 15, pg = t >> 4;
  const float* F  = F2 + (size_t)s * LL * LL;
  const float* mm = mmv + s * LL;
  __shared__ float red[16][17];
  float mx = -1e30f;
  for (int j = 0; j < 64; ++j) {
    int p = pg + 16 * j;
    float v = F[(size_t)p * LL + q0 + qx] * mm[p] * 10.f;
    mx = fmaxf(mx, v);
  }
  red[pg][qx] = mx;
  __syncthreads();
  float m = -1e30f;
  for (int i = 0; i < 16; ++i) m = fmaxf(m, red[i][qx]);
  __syncthreads();
  float sm = 0.f;
  for (int j = 0; j < 64; ++j) {
    int p = pg + 16 * j;
    float v = F[(size_t)p * LL + q0 + qx] * mm[p] * 10.f;
    sm += __expf(v - m);
  }
  red[pg][qx] = sm;
  __syncthreads();
  float tot = 0.f;
  for (int i = 0; i < 16; ++i) tot += red[i][qx];
  float inv = 1.f / tot;
  float* yo = yiT + (size_t)s * LL * LL + (size_t)(q0 + qx) * LL;
  for (int j = 0; j < 64; ++j) {
    int p = pg * 64 + j;
    float v = F[(size_t)p * LL + q0 + qx] * mm[p] * 10.f;
    yo[p] = __expf(v - m) * inv * mm[p];
  }
}

// ---------------- deconv: per parity class, out = (1/4) * Bcl[c][k] . Acl[k][q']
// Acl gathered on the fly from yiT with <=4 diagonal taps
__global__ __launch_bounds__(256) void deconv(const float* __restrict__ yiT,
                                              const float* __restrict__ bpT,
                                              float* __restrict__ out) {
  int z   = blockIdx.z;            // s*4 + cls
  int s   = z >> 2, cls = z & 3;
  int py  = cls >> 1, px = cls & 1;
  int sy  = py ? 1 : -1;
  int sx  = px ? 1 : -1;
  int m0  = blockIdx.y * 64;       // c
  int n0  = blockIdx.x * 64;       // q' = (i',j')
  const float* Y  = yiT + (size_t)s * LL * LL;  // [fg q][bg k]
  const float* Bp = bpT + (size_t)z * LL * NC;  // [k][c]
  __shared__ float As[16][64];     // [kk][q']
  __shared__ float Bs[16][64];     // [kk][c]
  int t = threadIdx.x;
  int tx = t & 15, ty = t >> 4;
  float acc[4][4] = {};
  for (int k0 = 0; k0 < LL; k0 += 16) {
#pragma unroll
    for (int r = 0; r < 4; ++r) {
      int e  = t + r * 256;
      int kk = e >> 6, mm = e & 63;
      Bs[kk][mm] = Bp[(size_t)(k0 + kk) * NC + m0 + mm];
      int k  = k0 + kk;
      int kh = k >> 5, kw = k & 31;
      int qq = n0 + mm;
      int ih = qq >> 5, jw = qq & 31;
      float v = 0.f;
#pragma unroll
      for (int th = 0; th < 2; ++th)
#pragma unroll
        for (int tw = 0; tw < 2; ++tw) {
          int Shh = th ? sy : 0, Sww = tw ? sx : 0;
          int ih2 = ih + Shh, jw2 = jw + Sww, kh2 = kh + Shh, kw2 = kw + Sww;
          if (ih2 >= 0 && ih2 < 32 && jw2 >= 0 && jw2 < 32 &&
              kh2 >= 0 && kh2 < 32 && kw2 >= 0 && kw2 < 32)
            v += Y[(size_t)(ih2 * 32 + jw2) * LL + kh2 * 32 + kw2];
        }
      As[kk][mm] = v;
    }
    __syncthreads();
#pragma unroll
    for (int kk = 0; kk < 16; ++kk) {
      float4 av = *(const float4*)&Bs[kk][ty * 4];
      float4 bv = *(const float4*)&As[kk][tx * 4];
      float a[4] = {av.x, av.y, av.z, av.w};
      float bb[4] = {bv.x, bv.y, bv.z, bv.w};
#pragma unroll
      for (int i = 0; i < 4; ++i)
#pragma unroll
        for (int j = 0; j < 4; ++j) acc[i][j] += a[i] * bb[j];
    }
    __syncthreads();
  }
#pragma unroll
  for (int i = 0; i < 4; ++i) {
    int c = m0 + ty * 4 + i;
#pragma unroll
    for (int j = 0; j < 4; ++j) {
      int qq = n0 + tx * 4 + j;
      int ih = qq >> 5, jw = qq & 31;
      out[((size_t)(s * NC + c) * HH + 2 * ih + py) * WW + 2 * jw + px] = acc[i][j] * 0.25f;
    }
  }
}

extern "C" void kernel_launch(void* const* d_in, const int* in_sizes, int n_in,
                              void* d_out, int out_size, void* d_ws, size_t ws_size,
                              hipStream_t stream) {
  const float* f    = (const float*)d_in[0];
  const float* b    = (const float*)d_in[1];
  const float* mask = (const float*)d_in[2];
  float* out  = (float*)d_out;

  // workspace layout (floats); total 11,542,528 floats = ~46.2 MB
  float* buf0 = (float*)d_ws;              // 4,194,304 (G -> F1 -> yiT)
  float* buf1 = buf0 + 4194304;            // 4,194,304 (S -> F2)
  float* fs   = buf1 + 4194304;            // 524,288
  float* bs   = fs + 524288;               // 524,288
  float* bpT  = bs + 524288;               // 2,097,152
  float* nrm  = bpT + 2097152;             // 4,096
  float* mmv  = nrm + 4096;                // 4,096

  hipLaunchKernelGGL(prep_fs_bs, dim3(2048), dim3(256), 0, stream, f, b, fs, bs);
  hipLaunchKernelGGL(prep_bparT, dim3(512), dim3(256), 0, stream, b, bpT);
  hipLaunchKernelGGL(gram, dim3(16, 16, 4), dim3(256), 0, stream, bs, fs, buf0);
  hipLaunchKernelGGL(norm_mm, dim3(4), dim3(1024), 0, stream, bs, mask, nrm, mmv);
  hipLaunchKernelGGL(sbuild, dim3(4, 1024, 4), dim3(256), 0, stream, buf0, nrm, buf1);
  hipLaunchKernelGGL(fuse1, dim3(4, 1024, 4), dim3(256), 0, stream, buf1, buf0);
  hipLaunchKernelGGL(fuse2, dim3(4, 1024, 4), dim3(256), 0, stream, buf0, buf1);
  hipLaunchKernelGGL(softmax_k, dim3(64, 4), dim3(256), 0, stream, buf1, mmv, buf0);
  hipLaunchKernelGGL(deconv, dim3(16, 2, 16), dim3(256), 0, stream, buf0, bpT, out);
}

// Round 2
// 260.999 us; speedup vs baseline: 1.6946x; 1.6946x over previous
//
#include <hip/hip_runtime.h>
#include <math.h>

#define NS 4
#define NC 128
#define HH 64
#define WW 64
#define LL 1024   // 32*32

typedef unsigned short u16;
typedef u16 u16x4 __attribute__((ext_vector_type(4)));
typedef short s16x8 __attribute__((ext_vector_type(8)));
typedef float f32x4 __attribute__((ext_vector_type(4)));

__device__ __forceinline__ u16 f2bf(float x) {
  unsigned u = __float_as_uint(x);
  return (u16)((u + 0x7FFFu + ((u >> 16) & 1u)) >> 16);
}

// ---------------- prep: f_s [s][c][q], b_s [s][c][p]  (stride-2 subsample, c-major)
__global__ __launch_bounds__(256) void prep_fs_bs(const float* __restrict__ f,
                                                  const float* __restrict__ b,
                                                  float* __restrict__ fs,
                                                  float* __restrict__ bs) {
  int idx = blockIdx.x * 256 + threadIdx.x;      // NS*NC*LL = 524288
  if (idx >= NS * NC * LL) return;
  int q  = idx & (LL - 1);
  int c  = (idx >> 10) & (NC - 1);
  int s  = idx >> 17;
  int qh = q >> 5, qw = q & 31;
  int g  = ((s * NC + c) * HH + 2 * qh) * WW + 2 * qw;
  fs[idx] = f[g];
  bs[idx] = b[g];
}

// ---------------- prep: Wt[z][c][k] bf16 = b[s][c][2kh+py][2kw+px], k = kh*32+kw
__global__ __launch_bounds__(256) void prep_wt(const float* __restrict__ b,
                                               u16* __restrict__ Wt) {
  int q = blockIdx.x * 256 + threadIdx.x;        // 524288 quads
  int k4 = (q & 255) * 4;
  int c  = (q >> 8) & 127;
  int z  = q >> 15;
  int s = z >> 2, cls = z & 3, py = cls >> 1, px = cls & 1;
  int kh = k4 >> 5, kw = k4 & 31;
  const float* src = b + ((size_t)(s * NC + c) * HH + 2 * kh + py) * WW + px;
  u16x4 v;
#pragma unroll
  for (int i = 0; i < 4; ++i) v[i] = f2bf(src[2 * (kw + i)]);
  *(u16x4*)(Wt + (size_t)q * 4) = v;
}

// ---------------- Gram: G[s][p][q] = sum_c bs[s][c][p] * fs[s][c][q]   (M=N=1024, K=128)
__global__ __launch_bounds__(256) void gram(const float* __restrict__ bs,
                                            const float* __restrict__ fs,
                                            float* __restrict__ G) {
  int s  = blockIdx.z;
  int m0 = blockIdx.y * 64;
  int n0 = blockIdx.x * 64;
  const float* A  = bs + (size_t)s * NC * LL;
  const float* Bm = fs + (size_t)s * NC * LL;
  __shared__ float As[16][64];
  __shared__ float Bs2[16][64];
  int t = threadIdx.x;
  int tx = t & 15, ty = t >> 4;
  float acc[4][4] = {};
  for (int k0 = 0; k0 < NC; k0 += 16) {
#pragma unroll
    for (int r = 0; r < 4; ++r) {
      int e = t + r * 256;
      int kk = e >> 6, mm = e & 63;
      As[kk][mm]  = A[(k0 + kk) * LL + m0 + mm];
      Bs2[kk][mm] = Bm[(k0 + kk) * LL + n0 + mm];
    }
    __syncthreads();
#pragma unroll
    for (int kk = 0; kk < 16; ++kk) {
      float4 av = *(const float4*)&As[kk][ty * 4];
      float4 bv = *(const float4*)&Bs2[kk][tx * 4];
      float a[4] = {av.x, av.y, av.z, av.w};
      float bb[4] = {bv.x, bv.y, bv.z, bv.w};
#pragma unroll
      for (int i = 0; i < 4; ++i)
#pragma unroll
        for (int j = 0; j < 4; ++j) acc[i][j] += a[i] * bb[j];
    }
    __syncthreads();
  }
  float* Gs = G + (size_t)s * LL * LL;
#pragma unroll
  for (int i = 0; i < 4; ++i) {
    float4 o = make_float4(acc[i][0], acc[i][1], acc[i][2], acc[i][3]);
    *(float4*)&Gs[(size_t)(m0 + ty * 4 + i) * LL + n0 + tx * 4] = o;
  }
}

// ---------------- norms (patch L2 incl. +1e-4 per element) and mask means
__global__ __launch_bounds__(1024) void norm_mm(const float* __restrict__ bs,
                                                const float* __restrict__ mask,
                                                float* __restrict__ nrm,
                                                float* __restrict__ mmv) {
  int s = blockIdx.x;
  int p = threadIdx.x;             // 1024
  __shared__ float Q[LL];
  __shared__ float M[LL];
  const float* bsp = bs + (size_t)s * NC * LL;
  float q = 0.f;
  for (int c = 0; c < NC; ++c) { float v = bsp[c * LL + p]; q += v * v; }
  Q[p] = q;
  int ph = p >> 5, pw = p & 31;
  M[p] = mask[s * HH * WW + (2 * ph) * WW + 2 * pw];
  __syncthreads();
  float sum2 = 1152 * 1e-4f;       // sum of the +0.0001 terms (128*3*3)
  float msum = 0.f;
#pragma unroll
  for (int dh = -1; dh <= 1; ++dh)
#pragma unroll
    for (int dw = -1; dw <= 1; ++dw) {
      int h = ph + dh, w = pw + dw;
      if (h >= 0 && h < 32 && w >= 0 && w < 32) {
        sum2 += Q[h * 32 + w];
        msum += M[h * 32 + w];
      }
    }
  nrm[s * LL + p] = sqrtf(sum2);
  mmv[s * LL + p] = msum * (1.f / 9.f);
}

// ---------------- S[p][q] = (sum of 9 diagonal 2D taps of G) / norm[p]
__global__ __launch_bounds__(256) void sbuild(const float* __restrict__ G,
                                              const float* __restrict__ nrm,
                                              float* __restrict__ S) {
  int s = blockIdx.z;
  int p = blockIdx.y;
  int q = blockIdx.x * 256 + threadIdx.x;
  int ph = p >> 5, pw = p & 31, qh = q >> 5, qw = q & 31;
  const float* Gs = G + (size_t)s * LL * LL;
  float acc = 0.f;
#pragma unroll
  for (int dh = -1; dh <= 1; ++dh)
#pragma unroll
    for (int dw = -1; dw <= 1; ++dw) {
      int ph2 = ph + dh, pw2 = pw + dw, qh2 = qh + dh, qw2 = qw + dw;
      if (ph2 >= 0 && ph2 < 32 && pw2 >= 0 && pw2 < 32 &&
          qh2 >= 0 && qh2 < 32 && qw2 >= 0 && qw2 < 32)
        acc += Gs[(size_t)(ph2 * 32 + pw2) * LL + qh2 * 32 + qw2];
    }
  S[(size_t)s * LL * LL + (size_t)p * LL + q] = acc / nrm[s * LL + p];
}

// ---------------- fuse pass 1: flat diagonal 3-tap in (I,J)
__global__ __launch_bounds__(256) void fuse1(const float* __restrict__ S,
                                             float* __restrict__ F1) {
  int s = blockIdx.z;
  int I = blockIdx.y;
  int J = blockIdx.x * 256 + threadIdx.x;
  const float* Ss = S + (size_t)s * LL * LL;
  float v = Ss[(size_t)I * LL + J];
  if (I > 0 && J > 0)           v += Ss[(size_t)(I - 1) * LL + J - 1];
  if (I < LL - 1 && J < LL - 1) v += Ss[(size_t)(I + 1) * LL + J + 1];
  F1[(size_t)s * LL * LL + (size_t)I * LL + J] = v;
}

// ---------------- fuse pass 2: diagonal 3-tap in transposed flattening
__global__ __launch_bounds__(256) void fuse2(const float* __restrict__ F1,
                                             float* __restrict__ F2) {
  int s = blockIdx.z;
  int I = blockIdx.y;                        // ibh*32+ibw
  int J = blockIdx.x * 256 + threadIdx.x;    // fhi*32+fwi
  int ibh = I >> 5, ibw = I & 31, fhi = J >> 5, fwi = J & 31;
  int Ip = ibw * 32 + ibh, Jp = fwi * 32 + fhi;
  const float* F = F1 + (size_t)s * LL * LL;
  float v = 0.f;
#pragma unroll
  for (int d = -1; d <= 1; ++d) {
    int a = Ip + d, bb = Jp + d;
    if (a >= 0 && a < LL && bb >= 0 && bb < LL) {
      int I2 = (a & 31) * 32 + (a >> 5);
      int J2 = (bb & 31) * 32 + (bb >> 5);
      v += F[(size_t)I2 * LL + J2];
    }
  }
  F2[(size_t)s * LL * LL + (size_t)I * LL + J] = v;
}

// ---------------- column softmax over p (with mm applied pre/post), write transposed yiT[q][p]
__global__ __launch_bounds__(256) void softmax_k(const float* __restrict__ F2,
                                                 const float* __restrict__ mmv,
                                                 float* __restrict__ yiT) {
  int s  = blockIdx.y;
  int q0 = blockIdx.x * 16;
  int t  = threadIdx.x;
  int qx = t & 15, pg = t >> 4;
  const float* F  = F2 + (size_t)s * LL * LL;
  const float* mm = mmv + s * LL;
  __shared__ float red[16][17];
  float mx = -1e30f;
  for (int j = 0; j < 64; ++j) {
    int p = pg + 16 * j;
    float v = F[(size_t)p * LL + q0 + qx] * mm[p] * 10.f;
    mx = fmaxf(mx, v);
  }
  red[pg][qx] = mx;
  __syncthreads();
  float m = -1e30f;
  for (int i = 0; i < 16; ++i) m = fmaxf(m, red[i][qx]);
  __syncthreads();
  float sm = 0.f;
  for (int j = 0; j < 64; ++j) {
    int p = pg + 16 * j;
    float v = F[(size_t)p * LL + q0 + qx] * mm[p] * 10.f;
    sm += __expf(v - m);
  }
  red[pg][qx] = sm;
  __syncthreads();
  float tot = 0.f;
  for (int i = 0; i < 16; ++i) tot += red[i][qx];
  float inv = 1.f / tot;
  float* yo = yiT + (size_t)s * LL * LL + (size_t)(q0 + qx) * LL;
  for (int j = 0; j < 64; ++j) {
    int p = pg * 64 + j;
    float v = F[(size_t)p * LL + q0 + qx] * mm[p] * 10.f;
    yo[p] = __expf(v - m) * inv * mm[p];
  }
}

// ---------------- deconv via MFMA bf16:
// per z=(s,cls): out[c][n'] = 0.25 * sum_k Wt[z][c][k] * P[k][n'],
// P[k][n] = sum of <=4 diagonal taps of yiT (gathered on the fly into swizzled LDS)
__global__ __launch_bounds__(256) void deconv_mfma(const float* __restrict__ yiT,
                                                   const u16* __restrict__ Wt,
                                                   float* __restrict__ out) {
  int z = blockIdx.y;              // s*4 + cls
  int s = z >> 2, cls = z & 3;
  int py = cls >> 1, px = cls & 1;
  int sy = py ? 1 : -1, sx = px ? 1 : -1;
  int n0 = blockIdx.x * 32;

  __shared__ __align__(16) u16 Pt[32 * 64];   // swizzled [n][k], rows 128B

  const float* Y = yiT + (size_t)s * LL * LL;
  const u16* Wz = Wt + (size_t)z * NC * LL;

  int t = threadIdx.x;
  // ---- gather role: thread owns (n = n0 + t&31, k-octet (t>>5)*8)
  int gn = t & 31;
  int n  = n0 + gn;
  int ih = n >> 5, jw = n & 31;
  int kloc = (t >> 5) * 8;
  int dy = sy * (32 * LL + 32);
  int dx = sx * (LL + 1);
  bool vyr = (unsigned)(ih + sy) < 32u;
  bool vxr = (unsigned)(jw + sx) < 32u;
  u16* wptr = (u16*)((char*)Pt + gn * 128 + ((kloc * 2) ^ ((gn & 7) << 4)));
  const float* gbase0 = Y + (size_t)n * LL + kloc;

  // ---- mfma role
  int lane = t & 63, wid = t >> 6;
  int mh = wid >> 1, nh = wid & 1;
  int lr = lane & 15, lg = lane >> 4;
  const u16* Arow[4];
#pragma unroll
  for (int mt = 0; mt < 4; ++mt)
    Arow[mt] = Wz + (size_t)(mh * 64 + mt * 16 + lr) * LL + lg * 8;
  int brow = nh * 16 + lr;
  const u16* bp0 = (const u16*)((char*)Pt + brow * 128 + ((lg * 16) ^ ((brow & 7) << 4)));
  const u16* bp1 = (const u16*)((char*)Pt + brow * 128 + ((64 + lg * 16) ^ ((brow & 7) << 4)));

  f32x4 acc[4] = {};
  float gA[8], gB[8], gC[8], gD[8];
  s16x8 Acur[4][2], Anext[4][2];

  // issue gather loads for chunk starting at k0 (loads only — sums deferred)
  auto GISSUE = [&](int k0) {
    int ksb = k0 + kloc;
    int kh2 = ksb >> 5;
    int kwb = ksb & 31;
    bool vy = vyr && ((unsigned)(kh2 + sy) < 32u);
    const float* base = gbase0 + k0;
#pragma unroll
    for (int e = 0; e < 8; ++e) {
      gA[e] = base[e];
      gB[e] = vy ? base[e + dy] : 0.f;
      bool vx = vxr && ((unsigned)(kwb + e + sx) < 32u);
      gC[e] = vx ? base[e + dx] : 0.f;
      gD[e] = (vx && vy) ? base[e + dx + dy] : 0.f;
    }
  };
  auto GSUMWRITE = [&]() {
    s16x8 pk;
#pragma unroll
    for (int e = 0; e < 8; ++e)
      pk[e] = (short)f2bf((gA[e] + gB[e]) + (gC[e] + gD[e]));
    *(s16x8*)wptr = pk;
  };
  auto AISSUE = [&](int k0, s16x8 A[4][2]) {
#pragma unroll
    for (int mt = 0; mt < 4; ++mt) {
      A[mt][0] = *(const s16x8*)(Arow[mt] + k0);
      A[mt][1] = *(const s16x8*)(Arow[mt] + k0 + 32);
    }
  };

  GISSUE(0);
  AISSUE(0, Acur);
  GSUMWRITE();
  __syncthreads();

#pragma unroll 1
  for (int ch = 0; ch < 16; ++ch) {
    if (ch < 15) {
      int k0n = (ch + 1) * 64;
      GISSUE(k0n);            // loads in flight, hidden under MFMA
      AISSUE(k0n, Anext);
    }
    s16x8 B0 = *(const s16x8*)bp0;
    s16x8 B1 = *(const s16x8*)bp1;
#pragma unroll
    for (int mt = 0; mt < 4; ++mt)
      acc[mt] = __builtin_amdgcn_mfma_f32_16x16x32_bf16(Acur[mt][0], B0, acc[mt], 0, 0, 0);
#pragma unroll
    for (int mt = 0; mt < 4; ++mt)
      acc[mt] = __builtin_amdgcn_mfma_f32_16x16x32_bf16(Acur[mt][1], B1, acc[mt], 0, 0, 0);
    __syncthreads();          // all waves done reading LDS
    if (ch < 15) {
      GSUMWRITE();            // waits for gather loads, writes next tile
#pragma unroll
      for (int mt = 0; mt < 4; ++mt) {
        Acur[mt][0] = Anext[mt][0];
        Acur[mt][1] = Anext[mt][1];
      }
    }
    __syncthreads();          // writes visible before next reads
  }

  // writeback: C/D layout col=lane&15 (n), row=(lane>>4)*4+reg (c)
  int nn = n0 + nh * 16 + lr;
  size_t obase = (size_t)(2 * (nn >> 5) + py) * WW + 2 * (nn & 31) + px;
#pragma unroll
  for (int mt = 0; mt < 4; ++mt) {
    int cbase = mh * 64 + mt * 16 + lg * 4;
#pragma unroll
    for (int r = 0; r < 4; ++r) {
      int c = cbase + r;
      out[(size_t)(s * NC + c) * (HH * WW) + obase] = acc[mt][r] * 0.25f;
    }
  }
}

extern "C" void kernel_launch(void* const* d_in, const int* in_sizes, int n_in,
                              void* d_out, int out_size, void* d_ws, size_t ws_size,
                              hipStream_t stream) {
  const float* f    = (const float*)d_in[0];
  const float* b    = (const float*)d_in[1];
  const float* mask = (const float*)d_in[2];
  float* out  = (float*)d_out;

  // workspace layout (floats); total ~38 MB
  float* buf0 = (float*)d_ws;              // 4,194,304 (G -> F1 -> yiT)
  float* buf1 = buf0 + 4194304;            // 4,194,304 (S -> F2)
  float* fs   = buf1 + 4194304;            // 524,288
  float* bs   = fs + 524288;               // 524,288
  u16*   Wt   = (u16*)(bs + 524288);       // 2,097,152 u16 (4 MB)
  float* nrm  = (float*)(Wt + 2097152);    // 4,096
  float* mmv  = nrm + 4096;                // 4,096

  hipLaunchKernelGGL(prep_fs_bs, dim3(2048), dim3(256), 0, stream, f, b, fs, bs);
  hipLaunchKernelGGL(prep_wt, dim3(2048), dim3(256), 0, stream, b, Wt);
  hipLaunchKernelGGL(gram, dim3(16, 16, 4), dim3(256), 0, stream, bs, fs, buf0);
  hipLaunchKernelGGL(norm_mm, dim3(4), dim3(1024), 0, stream, bs, mask, nrm, mmv);
  hipLaunchKernelGGL(sbuild, dim3(4, 1024, 4), dim3(256), 0, stream, buf0, nrm, buf1);
  hipLaunchKernelGGL(fuse1, dim3(4, 1024, 4), dim3(256), 0, stream, buf1, buf0);
  hipLaunchKernelGGL(fuse2, dim3(4, 1024, 4), dim3(256), 0, stream, buf0, buf1);
  hipLaunchKernelGGL(softmax_k, dim3(64, 4), dim3(256), 0, stream, buf1, mmv, buf0);
  hipLaunchKernelGGL(deconv_mfma, dim3(32, 16), dim3(256), 0, stream, buf0, Wt, out);
}